// Round 6
// baseline (453.760 us; speedup 1.0000x reference)
//
#include <hip/hip_runtime.h>

// Problem constants (from reference)
#define T_STEPS 1000
#define BATCH   16384
// X_DIM=3, Z_DIM=2, H_DIM=2, SIGMA=0.01

#define CH      40     // accumulated steps per regular chunk
#define NCHUNK  25     // total chunks (last accumulates 39)
#define WARM    20     // pure-RNN warm-up steps (contraction ~0.36^20)
#define TT      4      // timesteps per LDS tile
#define BLK     256    // threads per workgroup (4 waves); block owns 256 elements
#define NPART   (NCHUNK * (BATCH / BLK))   // 1600 partial sums

struct P {
    float w00,w01,w02,w10,w11,w12;
    float u00,u01,u10,u11,bs0,bs1;
    float wt00,wt01,wt10,wt11,bt0,bt1;
    float we00,we01,we10,we11,we20,we21,be0,be1,be2;
};

__device__ __forceinline__ float fast_tanh(float x) {
    float e = __expf(2.0f * x);
    return 1.0f - __fdividef(2.0f, e + 1.0f);
}

__device__ __forceinline__ void rnn_step(const P& p, float X0, float X1, float X2,
                                         float& h0, float& h1) {
    float p0 = p.bs0;
    p0 = __fmaf_rn(p.w00, X0, p0);
    p0 = __fmaf_rn(p.w01, X1, p0);
    p0 = __fmaf_rn(p.w02, X2, p0);
    p0 = __fmaf_rn(p.u00, h0, p0);
    p0 = __fmaf_rn(p.u01, h1, p0);
    float p1 = p.bs1;
    p1 = __fmaf_rn(p.w10, X0, p1);
    p1 = __fmaf_rn(p.w11, X1, p1);
    p1 = __fmaf_rn(p.w12, X2, p1);
    p1 = __fmaf_rn(p.u10, h0, p1);
    p1 = __fmaf_rn(p.u11, h1, p1);
    h0 = fast_tanh(p0);
    h1 = fast_tanh(p1);
}

__device__ __forceinline__ void body(const P& p, float X0, float X1, float X2,
                                     float E0, float E1,
                                     float& h0, float& h1, float& zp0, float& zp1,
                                     float& ssq, float& esq) {
    const float z0 = __fmaf_rn(0.01f, E0, h0);
    const float z1 = __fmaf_rn(0.01f, E1, h1);
    const float zl0 = __fmaf_rn(p.wt00, zp0, __fmaf_rn(p.wt01, zp1, p.bt0));
    const float zl1 = __fmaf_rn(p.wt10, zp0, __fmaf_rn(p.wt11, zp1, p.bt1));
    const float xl0 = __fmaf_rn(p.we00, z0, __fmaf_rn(p.we01, z1, p.be0));
    const float xl1 = __fmaf_rn(p.we10, z0, __fmaf_rn(p.we11, z1, p.be1));
    const float xl2 = __fmaf_rn(p.we20, z0, __fmaf_rn(p.we21, z1, p.be2));
    const float r0 = z0 - zl0;
    const float r1 = z1 - zl1;
    const float r2 = X0 - xl0;
    const float r3 = X1 - xl1;
    const float r4 = X2 - xl2;
    float s = r0 * r0;
    s = __fmaf_rn(r1, r1, s);
    s = __fmaf_rn(r2, r2, s);
    s = __fmaf_rn(r3, r3, s);
    s = __fmaf_rn(r4, r4, s);
    ssq += s;
    esq = __fmaf_rn(E0, E0, esq);
    esq = __fmaf_rn(E1, E1, esq);
    zp0 = z0; zp1 = z1;
    rnn_step(p, X0, X1, X2, h0, h1);
}

// Staged tile held in registers between load and write phases.
struct Stg {
    float4 d0, d1, d2;   // data row slice (wave w owns timestep tbase+w)
    float4 e0, e1;       // eps row slice
};

__device__ __forceinline__ void stage_load(const float* __restrict__ data,
        const float* __restrict__ eps, Stg& r,
        int tbase, int b0, int w, int lane, bool do_eps)
{
    const float4* srcd = reinterpret_cast<const float4*>(
        data + ((size_t)(tbase + w) * BATCH + b0) * 3);
    r.d0 = srcd[lane];
    r.d1 = srcd[lane + 64];
    r.d2 = srcd[lane + 128];
    if (do_eps) {
        const float4* srce = reinterpret_cast<const float4*>(
            eps + ((size_t)(tbase + w) * BATCH + b0) * 2);
        r.e0 = srce[lane];
        r.e1 = srce[lane + 64];
    }
}

__device__ __forceinline__ void stage_write(float* db, float* ebf, const Stg& r,
        int w, int lane, bool do_eps)
{
    float4* dd = reinterpret_cast<float4*>(db + w * (BLK * 3));
    dd[lane]       = r.d0;
    dd[lane + 64]  = r.d1;
    dd[lane + 128] = r.d2;
    if (do_eps) {
        float4* de = reinterpret_cast<float4*>(ebf + w * (BLK * 2));
        de[lane]      = r.e0;
        de[lane + 64] = r.e1;
    }
}

__device__ __forceinline__ void compute_warm4(const P& p, const float* db, int tid,
        float& h0, float& h1)
{
    const float* dp = db + tid * 3;
#pragma unroll
    for (int s = 0; s < TT; ++s)
        rnn_step(p, dp[s*BLK*3 + 0], dp[s*BLK*3 + 1], dp[s*BLK*3 + 2], h0, h1);
}

__device__ __forceinline__ void compute_body4(const P& p, const float* db,
        const float* ebf, int tid,
        float& h0, float& h1, float& zp0, float& zp1, float& ssq, float& esq)
{
    const float* dp = db + tid * 3;
    const float2* ep = reinterpret_cast<const float2*>(ebf) + tid;
#pragma unroll
    for (int s = 0; s < TT; ++s) {
        const float2 E = ep[s * BLK];
        body(p, dp[s*BLK*3 + 0], dp[s*BLK*3 + 1], dp[s*BLK*3 + 2],
             E.x, E.y, h0, h1, zp0, zp1, ssq, esq);
    }
}

// Mixed tile: nw warm steps, then transition (seed zp, rnn), then body rest.
__device__ __forceinline__ void compute_tr(const P& p, const float* db,
        const float* ebf, int tid, int nw,
        float& h0, float& h1, float& zp0, float& zp1, float& ssq, float& esq)
{
    const float* dp = db + tid * 3;
    const float2* ep = reinterpret_cast<const float2*>(ebf) + tid;
    for (int s = 0; s < TT; ++s) {
        const float X0 = dp[s*BLK*3 + 0];
        const float X1 = dp[s*BLK*3 + 1];
        const float X2 = dp[s*BLK*3 + 2];
        if (s < nw) {
            rnn_step(p, X0, X1, X2, h0, h1);
        } else if (s == nw) {
            const float2 E = ep[s * BLK];
            zp0 = __fmaf_rn(0.01f, E.x, h0);
            zp1 = __fmaf_rn(0.01f, E.y, h1);
            rnn_step(p, X0, X1, X2, h0, h1);
        } else {
            const float2 E = ep[s * BLK];
            body(p, X0, X1, X2, E.x, E.y, h0, h1, zp0, zp1, ssq, esq);
        }
    }
}

__global__ __launch_bounds__(BLK, 3)
void elbo_kernel(const float* __restrict__ data,
                 const float* __restrict__ eps,
                 const float* __restrict__ W_ih,
                 const float* __restrict__ W_hh,
                 const float* __restrict__ b_ih,
                 const float* __restrict__ b_hh,
                 const float* __restrict__ h0p,
                 const float* __restrict__ z0p,
                 const float* __restrict__ Wt,
                 const float* __restrict__ bt,
                 const float* __restrict__ We,
                 const float* __restrict__ be,
                 float* __restrict__ partial)
{
    __shared__ float dls0[TT * BLK * 3], dls1[TT * BLK * 3];   // 12 KB each
    __shared__ float els0[TT * BLK * 2], els1[TT * BLK * 2];   // 8 KB each

    const int tid  = threadIdx.x;
    const int w    = tid >> 6;
    const int lane = tid & 63;
    const int b0   = blockIdx.x * BLK;
    const int b    = b0 + tid;
    const int c    = blockIdx.y;             // 0..NCHUNK-1

    P p;
    p.w00 = W_ih[0]; p.w01 = W_ih[1]; p.w02 = W_ih[2];
    p.w10 = W_ih[3]; p.w11 = W_ih[4]; p.w12 = W_ih[5];
    p.u00 = W_hh[0]; p.u01 = W_hh[1]; p.u10 = W_hh[2]; p.u11 = W_hh[3];
    p.bs0 = b_ih[0] + b_hh[0];
    p.bs1 = b_ih[1] + b_hh[1];
    p.wt00 = Wt[0]; p.wt01 = Wt[1]; p.wt10 = Wt[2]; p.wt11 = Wt[3];
    p.bt0 = bt[0]; p.bt1 = bt[1];
    p.we00 = We[0]; p.we01 = We[1];
    p.we10 = We[2]; p.we11 = We[3];
    p.we20 = We[4]; p.we21 = We[5];
    p.be0 = be[0]; p.be1 = be[1]; p.be2 = be[2];

    float h0 = h0p[0], h1 = h0p[1];
    float zp0 = z0p[0], zp1 = z0p[1];
    float ssq = 0.0f, esq = 0.0f;

    // Prologue direct step (chunk 0: data[0]; middle chunks: data[c*CH-WARM]).
    if (c < NCHUNK - 1) {
        const int tpre = (c == 0) ? 0 : c * CH - WARM;
        const float* dpr = data + ((size_t)tpre * BATCH + b) * 3;
        rnn_step(p, dpr[0], dpr[1], dpr[2], h0, h1);
    }

    // Tile-run parameters (block-uniform).
    int tb, nt, trk, trnw, eps_from;
    if (c == 0) {
        tb = 1;                         nt = 10; trk = -1; trnw = 0; eps_from = 0;
    } else if (c < NCHUNK - 1) {
        tb = c * CH - WARM + 1;         nt = 15; trk = 4;  trnw = 3; eps_from = 4;
    } else {
        tb = (NCHUNK - 1) * CH - WARM;  nt = 15; trk = 5;  trnw = 0; eps_from = 5;
    }

    // Compact double-buffered pipeline: load(k+1) -> compute(k) -> write(k+1).
    {
        Stg r;
        stage_load(data, eps, r, tb, b0, w, lane, 0 >= eps_from);
        stage_write(dls0, els0, r, w, lane, 0 >= eps_from);
        __syncthreads();

        float* dcur = dls0; float* ecur = els0;
        float* dnxt = dls1; float* enxt = els1;
#pragma unroll 1
        for (int k = 0; k < nt; ++k) {
            const bool pf = (k + 1 < nt);
            const bool pe = (k + 1 >= eps_from);
            if (pf) stage_load(data, eps, r, tb + (k + 1) * TT, b0, w, lane, pe);

            if (k < trk)
                compute_warm4(p, dcur, tid, h0, h1);
            else if (k == trk)
                compute_tr(p, dcur, ecur, tid, trnw, h0, h1, zp0, zp1, ssq, esq);
            else
                compute_body4(p, dcur, ecur, tid, h0, h1, zp0, zp1, ssq, esq);

            if (pf) stage_write(dnxt, enxt, r, w, lane, pe);
            __syncthreads();
            float* td = dcur; dcur = dnxt; dnxt = td;
            float* te = ecur; ecur = enxt; enxt = te;
        }
    }

    const int na = (c < NCHUNK - 1) ? CH : (T_STEPS - 1 - (NCHUNK - 1) * CH);
    // Per-step constant: 3 net terms of (-ln(sigma) - 0.5*ln(2*pi))
    const float CPT = (float)na * (3.0f * 3.6862316527806026f);
    float tval = __fmaf_rn(ssq, -5000.0f, __fmaf_rn(esq, 0.5f, CPT));

    // wave reduction, then cross-wave via LDS
#pragma unroll
    for (int off = 32; off >= 1; off >>= 1)
        tval += __shfl_down(tval, off, 64);

    __shared__ float sm[BLK / 64];
    if ((tid & 63) == 0) sm[tid >> 6] = tval;
    __syncthreads();
    if (tid == 0) {
        float s = sm[0];
#pragma unroll
        for (int j = 1; j < BLK / 64; ++j) s += sm[j];
        partial[c * (BATCH / BLK) + blockIdx.x] = s;
    }
}

__global__ __launch_bounds__(256)
void reduce_kernel(const float* __restrict__ partial, float* __restrict__ out)
{
    float s = 0.0f;
    for (int i = threadIdx.x; i < NPART; i += 256)
        s += partial[i];
    __shared__ float sm[4];
#pragma unroll
    for (int off = 32; off >= 1; off >>= 1)
        s += __shfl_down(s, off, 64);
    if ((threadIdx.x & 63) == 0) sm[threadIdx.x >> 6] = s;
    __syncthreads();
    if (threadIdx.x == 0)
        out[0] = sm[0] + sm[1] + sm[2] + sm[3];
}

extern "C" void kernel_launch(void* const* d_in, const int* in_sizes, int n_in,
                              void* d_out, int out_size, void* d_ws, size_t ws_size,
                              hipStream_t stream) {
    const float* data = (const float*)d_in[0];
    const float* eps  = (const float*)d_in[1];
    const float* W_ih = (const float*)d_in[2];
    const float* W_hh = (const float*)d_in[3];
    const float* b_ih = (const float*)d_in[4];
    const float* b_hh = (const float*)d_in[5];
    const float* h0   = (const float*)d_in[6];
    const float* z0   = (const float*)d_in[7];
    const float* Wt   = (const float*)d_in[8];
    const float* bt   = (const float*)d_in[9];
    const float* We   = (const float*)d_in[10];
    const float* be   = (const float*)d_in[11];
    float* out     = (float*)d_out;
    float* partial = (float*)d_ws;

    elbo_kernel<<<dim3(BATCH / BLK, NCHUNK), dim3(BLK), 0, stream>>>(
        data, eps, W_ih, W_hh, b_ih, b_hh, h0, z0, Wt, bt, We, be, partial);
    reduce_kernel<<<dim3(1), dim3(256), 0, stream>>>(partial, out);
}

// Round 7
// 390.393 us; speedup vs baseline: 1.1623x; 1.1623x over previous
//
#include <hip/hip_runtime.h>

// Problem constants (from reference)
#define T_STEPS 1000
#define BATCH   16384
// X_DIM=3, Z_DIM=2, H_DIM=2, SIGMA=0.01

#define CH      40     // accumulated steps per regular chunk
#define NCHUNK  25     // total chunks (last accumulates 39)
#define WARM    20     // pure-RNN warm-up steps (contraction ~0.36^20)
#define TT      4      // timesteps per LDS tile
#define BLK     256    // threads per workgroup (4 waves); block owns 256 elements
#define NPART   (NCHUNK * (BATCH / BLK))   // 1600 partial sums

struct P {
    float w00,w01,w02,w10,w11,w12;
    float u00,u01,u10,u11,bs0,bs1;
    float wt00,wt01,wt10,wt11,bt0,bt1;
    float we00,we01,we10,we11,we20,we21,be0,be1,be2;
};

__device__ __forceinline__ float fast_tanh(float x) {
    float e = __expf(2.0f * x);
    return 1.0f - __fdividef(2.0f, e + 1.0f);
}

__device__ __forceinline__ void rnn_step(const P& p, float X0, float X1, float X2,
                                         float& h0, float& h1) {
    float p0 = p.bs0;
    p0 = __fmaf_rn(p.w00, X0, p0);
    p0 = __fmaf_rn(p.w01, X1, p0);
    p0 = __fmaf_rn(p.w02, X2, p0);
    p0 = __fmaf_rn(p.u00, h0, p0);
    p0 = __fmaf_rn(p.u01, h1, p0);
    float p1 = p.bs1;
    p1 = __fmaf_rn(p.w10, X0, p1);
    p1 = __fmaf_rn(p.w11, X1, p1);
    p1 = __fmaf_rn(p.w12, X2, p1);
    p1 = __fmaf_rn(p.u10, h0, p1);
    p1 = __fmaf_rn(p.u11, h1, p1);
    h0 = fast_tanh(p0);
    h1 = fast_tanh(p1);
}

__device__ __forceinline__ void body(const P& p, float X0, float X1, float X2,
                                     float E0, float E1,
                                     float& h0, float& h1, float& zp0, float& zp1,
                                     float& ssq, float& esq) {
    const float z0 = __fmaf_rn(0.01f, E0, h0);
    const float z1 = __fmaf_rn(0.01f, E1, h1);
    const float zl0 = __fmaf_rn(p.wt00, zp0, __fmaf_rn(p.wt01, zp1, p.bt0));
    const float zl1 = __fmaf_rn(p.wt10, zp0, __fmaf_rn(p.wt11, zp1, p.bt1));
    const float xl0 = __fmaf_rn(p.we00, z0, __fmaf_rn(p.we01, z1, p.be0));
    const float xl1 = __fmaf_rn(p.we10, z0, __fmaf_rn(p.we11, z1, p.be1));
    const float xl2 = __fmaf_rn(p.we20, z0, __fmaf_rn(p.we21, z1, p.be2));
    const float r0 = z0 - zl0;
    const float r1 = z1 - zl1;
    const float r2 = X0 - xl0;
    const float r3 = X1 - xl1;
    const float r4 = X2 - xl2;
    float s = r0 * r0;
    s = __fmaf_rn(r1, r1, s);
    s = __fmaf_rn(r2, r2, s);
    s = __fmaf_rn(r3, r3, s);
    s = __fmaf_rn(r4, r4, s);
    ssq += s;
    esq = __fmaf_rn(E0, E0, esq);
    esq = __fmaf_rn(E1, E1, esq);
    zp0 = z0; zp1 = z1;
    rnn_step(p, X0, X1, X2, h0, h1);
}

__device__ __forceinline__ void compute_warm4(const P& p, const float* db, int tid,
        float& h0, float& h1)
{
    const float* dp = db + tid * 3;
#pragma unroll
    for (int s = 0; s < TT; ++s)
        rnn_step(p, dp[s*BLK*3 + 0], dp[s*BLK*3 + 1], dp[s*BLK*3 + 2], h0, h1);
}

__device__ __forceinline__ void compute_body4(const P& p, const float* db,
        const float* ebf, int tid,
        float& h0, float& h1, float& zp0, float& zp1, float& ssq, float& esq)
{
    const float* dp = db + tid * 3;
    const float2* ep = reinterpret_cast<const float2*>(ebf) + tid;
#pragma unroll
    for (int s = 0; s < TT; ++s) {
        const float2 E = ep[s * BLK];
        body(p, dp[s*BLK*3 + 0], dp[s*BLK*3 + 1], dp[s*BLK*3 + 2],
             E.x, E.y, h0, h1, zp0, zp1, ssq, esq);
    }
}

// Mixed tile: nw warm steps, then transition (seed zp, rnn), then body rest.
__device__ __forceinline__ void compute_tr(const P& p, const float* db,
        const float* ebf, int tid, int nw,
        float& h0, float& h1, float& zp0, float& zp1, float& ssq, float& esq)
{
    const float* dp = db + tid * 3;
    const float2* ep = reinterpret_cast<const float2*>(ebf) + tid;
    for (int s = 0; s < TT; ++s) {
        const float X0 = dp[s*BLK*3 + 0];
        const float X1 = dp[s*BLK*3 + 1];
        const float X2 = dp[s*BLK*3 + 2];
        if (s < nw) {
            rnn_step(p, X0, X1, X2, h0, h1);
        } else if (s == nw) {
            const float2 E = ep[s * BLK];
            zp0 = __fmaf_rn(0.01f, E.x, h0);
            zp1 = __fmaf_rn(0.01f, E.y, h1);
            rnn_step(p, X0, X1, X2, h0, h1);
        } else {
            const float2 E = ep[s * BLK];
            body(p, X0, X1, X2, E.x, E.y, h0, h1, zp0, zp1, ssq, esq);
        }
    }
}

__global__ __launch_bounds__(BLK, 2)
void elbo_kernel(const float* __restrict__ data,
                 const float* __restrict__ eps,
                 const float* __restrict__ W_ih,
                 const float* __restrict__ W_hh,
                 const float* __restrict__ b_ih,
                 const float* __restrict__ b_hh,
                 const float* __restrict__ h0p,
                 const float* __restrict__ z0p,
                 const float* __restrict__ Wt,
                 const float* __restrict__ bt,
                 const float* __restrict__ We,
                 const float* __restrict__ be,
                 float* __restrict__ partial)
{
    __shared__ float dls[2][TT * BLK * 3];   // 12 KB each buffer
    __shared__ float els[2][TT * BLK * 2];   // 8 KB each buffer

    const int tid  = threadIdx.x;
    const int w    = tid >> 6;
    const int lane = tid & 63;
    const int b0   = blockIdx.x * BLK;
    const int b    = b0 + tid;
    const int c    = blockIdx.y;             // 0..NCHUNK-1

    P p;
    p.w00 = W_ih[0]; p.w01 = W_ih[1]; p.w02 = W_ih[2];
    p.w10 = W_ih[3]; p.w11 = W_ih[4]; p.w12 = W_ih[5];
    p.u00 = W_hh[0]; p.u01 = W_hh[1]; p.u10 = W_hh[2]; p.u11 = W_hh[3];
    p.bs0 = b_ih[0] + b_hh[0];
    p.bs1 = b_ih[1] + b_hh[1];
    p.wt00 = Wt[0]; p.wt01 = Wt[1]; p.wt10 = Wt[2]; p.wt11 = Wt[3];
    p.bt0 = bt[0]; p.bt1 = bt[1];
    p.we00 = We[0]; p.we01 = We[1];
    p.we10 = We[2]; p.we11 = We[3];
    p.we20 = We[4]; p.we21 = We[5];
    p.be0 = be[0]; p.be1 = be[1]; p.be2 = be[2];

    float h0 = h0p[0], h1 = h0p[1];
    float zp0 = z0p[0], zp1 = z0p[1];
    float ssq = 0.0f, esq = 0.0f;

    // Prologue direct step (chunk 0: data[0]; middle chunks: data[c*CH-WARM]).
    if (c < NCHUNK - 1) {
        const int tpre = (c == 0) ? 0 : c * CH - WARM;
        const float* dpr = data + ((size_t)tpre * BATCH + b) * 3;
        rnn_step(p, dpr[0], dpr[1], dpr[2], h0, h1);
    }

    // Tile-run parameters (block-uniform).
    int tb, nt, trk, trnw;
    if (c == 0) {
        tb = 1;                         nt = 10; trk = -1; trnw = 0;
    } else if (c < NCHUNK - 1) {
        tb = c * CH - WARM + 1;         nt = 15; trk = 4;  trnw = 3;
    } else {
        tb = (NCHUNK - 1) * CH - WARM;  nt = 15; trk = 5;  trnw = 0;
    }

    // Per-wave source row pointers (wave w owns timestep tbase+w of each tile).
    // All staging is UNCONDITIONAL: named float4 regs, always loaded, always
    // written (last iteration re-loads tile base into the dead buffer).
    {
        // stage tile 0 into buffer 0
        const float4* sd = reinterpret_cast<const float4*>(
            data + ((size_t)(tb + w) * BATCH + b0) * 3);
        const float4* se = reinterpret_cast<const float4*>(
            eps + ((size_t)(tb + w) * BATCH + b0) * 2);
        float4 rd0 = sd[lane], rd1 = sd[lane + 64], rd2 = sd[lane + 128];
        float4 re0 = se[lane], re1 = se[lane + 64];
        {
            float4* dd = reinterpret_cast<float4*>(&dls[0][w * (BLK * 3)]);
            dd[lane] = rd0; dd[lane + 64] = rd1; dd[lane + 128] = rd2;
            float4* de = reinterpret_cast<float4*>(&els[0][w * (BLK * 2)]);
            de[lane] = re0; de[lane + 64] = re1;
        }
        __syncthreads();

#pragma unroll 1
        for (int k = 0; k < nt; ++k) {
            // issue next-tile loads (clamped on last iteration; dead store)
            const int tl = (k + 1 < nt) ? tb + (k + 1) * TT : tb;
            const float4* nsd = reinterpret_cast<const float4*>(
                data + ((size_t)(tl + w) * BATCH + b0) * 3);
            const float4* nse = reinterpret_cast<const float4*>(
                eps + ((size_t)(tl + w) * BATCH + b0) * 2);
            rd0 = nsd[lane]; rd1 = nsd[lane + 64]; rd2 = nsd[lane + 128];
            re0 = nse[lane]; re1 = nse[lane + 64];

            const float* dcur = &dls[k & 1][0];
            const float* ecur = &els[k & 1][0];
            if (k < trk)
                compute_warm4(p, dcur, tid, h0, h1);
            else if (k == trk)
                compute_tr(p, dcur, ecur, tid, trnw, h0, h1, zp0, zp1, ssq, esq);
            else
                compute_body4(p, dcur, ecur, tid, h0, h1, zp0, zp1, ssq, esq);

            float* dd = reinterpret_cast<float4*>(&dls[(k + 1) & 1][w * (BLK * 3)])
                            ? (float*)&dls[(k + 1) & 1][0] : nullptr;
            (void)dd;
            {
                float4* wd = reinterpret_cast<float4*>(&dls[(k + 1) & 1][w * (BLK * 3)]);
                wd[lane] = rd0; wd[lane + 64] = rd1; wd[lane + 128] = rd2;
                float4* we_ = reinterpret_cast<float4*>(&els[(k + 1) & 1][w * (BLK * 2)]);
                we_[lane] = re0; we_[lane + 64] = re1;
            }
            __syncthreads();
        }
    }

    const int na = (c < NCHUNK - 1) ? CH : (T_STEPS - 1 - (NCHUNK - 1) * CH);
    // Per-step constant: 3 net terms of (-ln(sigma) - 0.5*ln(2*pi))
    const float CPT = (float)na * (3.0f * 3.6862316527806026f);
    float tval = __fmaf_rn(ssq, -5000.0f, __fmaf_rn(esq, 0.5f, CPT));

    // wave reduction, then cross-wave via LDS
#pragma unroll
    for (int off = 32; off >= 1; off >>= 1)
        tval += __shfl_down(tval, off, 64);

    __shared__ float sm[BLK / 64];
    if ((tid & 63) == 0) sm[tid >> 6] = tval;
    __syncthreads();
    if (tid == 0) {
        float s = sm[0];
#pragma unroll
        for (int j = 1; j < BLK / 64; ++j) s += sm[j];
        partial[c * (BATCH / BLK) + blockIdx.x] = s;
    }
}

__global__ __launch_bounds__(256)
void reduce_kernel(const float* __restrict__ partial, float* __restrict__ out)
{
    float s = 0.0f;
    for (int i = threadIdx.x; i < NPART; i += 256)
        s += partial[i];
    __shared__ float sm[4];
#pragma unroll
    for (int off = 32; off >= 1; off >>= 1)
        s += __shfl_down(s, off, 64);
    if ((threadIdx.x & 63) == 0) sm[threadIdx.x >> 6] = s;
    __syncthreads();
    if (threadIdx.x == 0)
        out[0] = sm[0] + sm[1] + sm[2] + sm[3];
}

extern "C" void kernel_launch(void* const* d_in, const int* in_sizes, int n_in,
                              void* d_out, int out_size, void* d_ws, size_t ws_size,
                              hipStream_t stream) {
    const float* data = (const float*)d_in[0];
    const float* eps  = (const float*)d_in[1];
    const float* W_ih = (const float*)d_in[2];
    const float* W_hh = (const float*)d_in[3];
    const float* b_ih = (const float*)d_in[4];
    const float* b_hh = (const float*)d_in[5];
    const float* h0   = (const float*)d_in[6];
    const float* z0   = (const float*)d_in[7];
    const float* Wt   = (const float*)d_in[8];
    const float* bt   = (const float*)d_in[9];
    const float* We   = (const float*)d_in[10];
    const float* be   = (const float*)d_in[11];
    float* out     = (float*)d_out;
    float* partial = (float*)d_ws;

    elbo_kernel<<<dim3(BATCH / BLK, NCHUNK), dim3(BLK), 0, stream>>>(
        data, eps, W_ih, W_hh, b_ih, b_hh, h0, z0, Wt, bt, We, be, partial);
    reduce_kernel<<<dim3(1), dim3(256), 0, stream>>>(partial, out);
}